// Round 8
// baseline (456.170 us; speedup 1.0000x reference)
//
#include <hip/hip_runtime.h>
#include <type_traits>

#define NIN 784
#define BANKS 64
#define NLAYER 15
#define FAN 8
#define DD 10
#define NBF 640             // features per sample per layer
#define NSW 4               // samples per sample-group (per wave)
#define NSB_V5 8            // samples per block, v5f fallback
#define NSB_V8 16           // samples per block, v8 (4 groups x 4)

typedef float f32x2 __attribute__((ext_vector_type(2)));

// ---------------- Kernel A: input GEMM (pk-packed) ----------------
#define BM 128
#define BN 64
#define BK 16

__global__ __launch_bounds__(256)
void input_gemm(const float* __restrict__ x, const float* __restrict__ Wi,
                const float* __restrict__ bi, float* __restrict__ acts)
{
    __shared__ float As[BK][BM + 4];
    __shared__ float Bs[BK][BN + 4];
    const int tid = threadIdx.x;
    const int tx = tid & 15, ty = tid >> 4;
    const int m0 = blockIdx.x * BM;
    const int n0 = blockIdx.y * BN;

    f32x2 acc2[8][2];
#pragma unroll
    for (int i = 0; i < 8; ++i)
#pragma unroll
        for (int j = 0; j < 2; ++j) acc2[i][j] = f32x2{0.f, 0.f};

    for (int kb = 0; kb < NIN / BK; ++kb) {
#pragma unroll
        for (int i = 0; i < 2; ++i) {
            int flat = tid + 256 * i;
            int m = flat >> 2, kq = flat & 3;
            float4 v = *(const float4*)(x + (m0 + m) * NIN + kb * BK + kq * 4);
            As[kq*4+0][m] = v.x; As[kq*4+1][m] = v.y;
            As[kq*4+2][m] = v.z; As[kq*4+3][m] = v.w;
        }
        {
            int n = tid >> 2, kq = tid & 3;
            float4 v = *(const float4*)(Wi + (n0 + n) * NIN + kb * BK + kq * 4);
            Bs[kq*4+0][n] = v.x; Bs[kq*4+1][n] = v.y;
            Bs[kq*4+2][n] = v.z; Bs[kq*4+3][n] = v.w;
        }
        __syncthreads();
#pragma unroll
        for (int k = 0; k < BK; ++k) {
            float4 a0 = *(const float4*)(&As[k][ty*8]);
            float4 a1 = *(const float4*)(&As[k][ty*8+4]);
            float4 bb = *(const float4*)(&Bs[k][tx*4]);
            float av[8] = {a0.x,a0.y,a0.z,a0.w,a1.x,a1.y,a1.z,a1.w};
            f32x2 bv2[2] = { f32x2{bb.x, bb.y}, f32x2{bb.z, bb.w} };
#pragma unroll
            for (int i = 0; i < 8; ++i) {
                f32x2 ai = f32x2{av[i], av[i]};
#pragma unroll
                for (int j = 0; j < 2; ++j)
                    acc2[i][j] = __builtin_elementwise_fma(ai, bv2[j], acc2[i][j]);
            }
        }
        __syncthreads();
    }
    float4 bv = *(const float4*)(bi + n0 + tx*4);
#pragma unroll
    for (int i = 0; i < 8; ++i) {
        int row = m0 + ty*8 + i;
        float4 o;
        o.x = fmaxf(acc2[i][0][0] + bv.x, 0.f);
        o.y = fmaxf(acc2[i][0][1] + bv.y, 0.f);
        o.z = fmaxf(acc2[i][1][0] + bv.z, 0.f);
        o.w = fmaxf(acc2[i][1][1] + bv.w, 0.f);
        *(float4*)(acts + row * NBF + n0 + tx*4) = o;
    }
}

__device__ __forceinline__ float f4c_rt(const float4& v, int c) {
    return c == 0 ? v.x : (c == 1 ? v.y : (c == 2 ? v.z : v.w));
}

typedef const __attribute__((address_space(1))) void gas_void;
typedef __attribute__((address_space(3))) void las_void;

__device__ __forceinline__ void gll16(const void* g, void* l) {
    __builtin_amdgcn_global_load_lds((gas_void*)g, (las_void*)l, 16, 0, 0);
}

// ---------------- Kernel T: weight pre-transpose ----------------
// chunk_t[l][k][r=0..27][bank] float4:
//   r<25 : Wd[l][bank][k] floats 4r..4r+3
//   r>=25: Wg[l][bank][k] floats 4(r-25)..+3 (zero-padded past 10)
// bias_t[l][q=0..1][bank] float4 = bg[l][bank][4q..4q+3]
#define NCH (NLAYER*FAN*28*64)   // 215040
#define NBI (NLAYER*2*64)        // 1920

__global__ __launch_bounds__(256)
void transpose_weights(const float* __restrict__ Wg, const float* __restrict__ bg,
                       const float* __restrict__ Wd,
                       float4* __restrict__ chunk_t, float4* __restrict__ bias_t)
{
    int tid = blockIdx.x * 256 + threadIdx.x;
    if (tid < NCH) {
        int b = tid & 63;
        int rk = tid >> 6;
        int r = rk % 28;
        int lk = rk / 28;           // l*8+k
        int k = lk & 7;
        int l = lk >> 3;
        float4 v;
        if (r < 25) {
            v = ((const float4*)Wd)[(((size_t)(l*64+b)*8 + k)*25) + r];
        } else {
            int q = r - 25;
            size_t base = ((size_t)(l*64+b)*8 + k)*10 + 4*q;
            float t[4];
#pragma unroll
            for (int c = 0; c < 4; ++c)
                t[c] = (4*q + c < 10) ? Wg[base + c] : 0.f;
            v = make_float4(t[0], t[1], t[2], t[3]);
        }
        chunk_t[tid] = v;
    } else if (tid < NCH + NBI) {
        int t2 = tid - NCH;
        int b = t2 & 63;
        int q = (t2 >> 6) & 1;
        int l = t2 >> 7;
        bias_t[t2] = ((const float4*)bg)[(size_t)(l*64+b)*2 + q];
    }
}

// ---------------- v8: 8 waves, ring-3 LDS, 1 barrier/chunk, pk-FMA ----------------
// Block = 8 waves: g = w&3 (sample group of 4), H = w>>2 (e-half). lane = bank.
// Chunk m staged into stg[m%3] (32 rows: 0-24 Wd, 25-27 Wg, 28-31 bias dup),
// 4 gll16/wave/chunk (uniform vmcnt). One barrier per chunk:
//   issue stage(m+1) -> buf (m+1)%3   [readers done since barrier m-1]
//   s_waitcnt vmcnt(4)                [own chunk-m rows landed]
//   s_barrier                         [all rows landed]
//   compute chunk m from buf m%3
// Samples packed in f32x2 pairs -> v_pk_fma_f32. Exchange via xbuf, barrier
// merged with next chunk-0's barrier.
template<int H>
__device__ __forceinline__
void rn8_path(const float* __restrict__ acts0,
              const float4* __restrict__ chunk_t,
              const float4* __restrict__ bias_t,
              const float* __restrict__ Wo,
              float* __restrict__ out,
              unsigned int* __restrict__ nopen_g,
              float4* __restrict__ stg,     // [3][32][64]
              float* __restrict__ xb,       // [2][4][NSW][5][64]
              const int lane, const int w, const int g, const int b0)
{
    // packed activations: A2[p][d] = {a(2p)[d], a(2p+1)[d]}
    f32x2 A2[2][DD];
#pragma unroll
    for (int p = 0; p < 2; ++p) {
        const float2* q0 = (const float2*)(acts0 + (size_t)(b0 + 2*p    ) * NBF + lane * DD);
        const float2* q1 = (const float2*)(acts0 + (size_t)(b0 + 2*p + 1) * NBF + lane * DD);
#pragma unroll
        for (int d2 = 0; d2 < 5; ++d2) {
            float2 v0 = q0[d2], v1 = q1[d2];
            A2[p][2*d2  ] = f32x2{v0.x, v1.x};
            A2[p][2*d2+1] = f32x2{v0.y, v1.y};
        }
    }

    f32x2 gs2[2] = { f32x2{0.f,0.f}, f32x2{0.f,0.f} };
    unsigned int nop = 0;

    auto stage_issue = [&](int m) {
        const int dst = m % 3;
        const int lst = m >> 3;                       // layer of chunk m
        const float4* cb = chunk_t + (size_t)m * (28*64) + lane;
        float4* db = stg + (size_t)dst * (32*64);
#pragma unroll
        for (int j = 0; j < 4; ++j) {
            const int r = w + 8*j;                    // rows w, w+8, w+16, w+24
            if (r < 28) gll16(cb + r*64, db + r*64);
            else        gll16(bias_t + (size_t)(lst*2 + ((r-28)&1))*64 + lane, db + r*64);
        }
    };

    stage_issue(0);
    asm volatile("s_waitcnt vmcnt(0)" ::: "memory");  // drain stage(0) + A2 loads

    for (int l = 0; l < NLAYER; ++l) {
        float acc[NSW][5];
#pragma unroll
        for (int s = 0; s < NSW; ++s)
#pragma unroll
            for (int el = 0; el < 5; ++el) acc[s][el] = 0.f;

#pragma unroll
        for (int c = 0; c < 8; ++c) {
            const int m = l*8 + c;
            const int cur = m % 3;

            if (m + 1 < NLAYER*8) {
                stage_issue(m + 1);
                asm volatile("s_waitcnt vmcnt(4)" ::: "memory");
            } else {
                asm volatile("s_waitcnt vmcnt(0)" ::: "memory");
            }
            asm volatile("s_barrier" ::: "memory");

            // chunk-0: pull exchanged half from previous layer
            if (c == 0 && l > 0) {
                if (H == 0) {
#pragma unroll
                    for (int s = 0; s < NSW; ++s)
#pragma unroll
                        for (int el = 0; el < 5; ++el)
                            A2[s>>1][5+el][s&1] = xb[(((0*4+g)*NSW+s)*5+el)*64 + lane];
                } else {
#pragma unroll
                    for (int s = 0; s < NSW; ++s)
#pragma unroll
                        for (int el = 0; el < 5; ++el)
                            A2[s>>1][el][s&1] = xb[(((1*4+g)*NSW+s)*5+el)*64 + lane];
                }
            }

            const int k = c;
            const float4* bufr = stg + (size_t)cur * (32*64);

            float4 wgq0 = bufr[25*64 + lane];
            float4 wgq1 = bufr[26*64 + lane];
            float4 wgq2 = bufr[27*64 + lane];
            float4 brow = bufr[(28 + (k >> 2))*64 + lane];
            float4 wv[13];
#pragma unroll
            for (int r = 0; r < 13; ++r) wv[r] = bufr[(12*H + r)*64 + lane];

            float wgv[DD];
#pragma unroll
            for (int d = 0; d < DD; ++d) {
                const float4& q = (d < 4) ? wgq0 : (d < 8 ? wgq1 : wgq2);
                wgv[d] = f4c_rt(q, d & 3);
            }
            const float bias = f4c_rt(brow, k & 3);

            // gates (packed over sample pairs)
            f32x2 gz[2];
#pragma unroll
            for (int p = 0; p < 2; ++p) {
                f32x2 z = f32x2{bias, bias};
#pragma unroll
                for (int d = 0; d < DD; ++d)
                    z = __builtin_elementwise_fma(A2[p][d], f32x2{wgv[d], wgv[d]}, z);
                f32x2 gate = __builtin_elementwise_min(
                                 __builtin_elementwise_max(z, f32x2{0.f, 0.f}),
                                 f32x2{1.f, 1.f});
                if (H == 0) {
                    gs2[p] += gate;
                    nop += (z[0] > 0.f) ? 1u : 0u;
                    nop += (z[1] > 0.f) ? 1u : 0u;
                }
                gz[p] = gate;
            }

            // data dots (packed), rotate by k, accumulate
            const int src = (lane - k) & 63;
#pragma unroll
            for (int el = 0; el < 5; ++el) {
#pragma unroll
                for (int p = 0; p < 2; ++p) {
                    f32x2 dot = f32x2{0.f, 0.f};
#pragma unroll
                    for (int d = 0; d < DD; ++d) {
                        const int idx = (5*H + el) * 10 + d - 48*H;
                        const float wd = f4c_rt(wv[idx >> 2], idx & 3);
                        dot = __builtin_elementwise_fma(A2[p][d], f32x2{wd, wd}, dot);
                    }
                    f32x2 cc = gz[p] * dot;
                    acc[2*p  ][el] += __shfl(cc[0], src, 64);
                    acc[2*p+1][el] += __shfl(cc[1], src, 64);
                }
            }
        }

        // layer end: ReLU own half, publish to xbuf (barrier = next chunk-0's)
        if (H == 0) {
#pragma unroll
            for (int s = 0; s < NSW; ++s)
#pragma unroll
                for (int el = 0; el < 5; ++el) {
                    float v = fmaxf(acc[s][el], 0.f);
                    A2[s>>1][el][s&1] = v;
                    if (l + 1 < NLAYER)
                        xb[(((1*4+g)*NSW+s)*5+el)*64 + lane] = v;   // ab=1 -> H1
                }
        } else {
#pragma unroll
            for (int s = 0; s < NSW; ++s)
#pragma unroll
                for (int el = 0; el < 5; ++el) {
                    float v = fmaxf(acc[s][el], 0.f);
                    A2[s>>1][5+el][s&1] = v;
                    xb[(((0*4+g)*NSW+s)*5+el)*64 + lane] = v;       // ab=0 -> H0
                }
        }
        asm volatile("s_waitcnt lgkmcnt(0)" ::: "memory");
    }

    asm volatile("s_barrier" ::: "memory");

    if (H == 0) {
        // final d5-9 from H1
#pragma unroll
        for (int s = 0; s < NSW; ++s)
#pragma unroll
            for (int el = 0; el < 5; ++el)
                A2[s>>1][5+el][s&1] = xb[(((0*4+g)*NSW+s)*5+el)*64 + lane];

        float wo[DD];
        const float2* pw = (const float2*)(Wo + lane * DD);
#pragma unroll
        for (int d2 = 0; d2 < 5; ++d2) {
            float2 v = pw[d2];
            wo[2*d2] = v.x; wo[2*d2+1] = v.y;
        }
#pragma unroll
        for (int p = 0; p < 2; ++p) {
            f32x2 o = f32x2{0.f, 0.f};
#pragma unroll
            for (int d = 0; d < DD; ++d)
                o = __builtin_elementwise_fma(A2[p][d], f32x2{wo[d], wo[d]}, o);
            out[(size_t)(b0 + 2*p    ) * BANKS + lane] = fmaxf(o[0], 0.f);
            out[(size_t)(b0 + 2*p + 1) * BANKS + lane] = fmaxf(o[1], 0.f);
        }

#pragma unroll
        for (int s = 0; s < NSW; ++s) {
            float v = gs2[s>>1][s&1];
#pragma unroll
            for (int off = 32; off; off >>= 1) v += __shfl_xor(v, off, 64);
            if (lane == 0)
                out[(size_t)4096 * BANKS + b0 + s] = v * (1.0f / 7680.0f);
        }
        {
            unsigned int v = nop;
#pragma unroll
            for (int off = 32; off; off >>= 1) v += __shfl_xor(v, off, 64);
            if (lane == 0) atomicAdd(nopen_g, v);
        }
    }
}

__global__ __launch_bounds__(512, 2)
void routenet_v8(const float* __restrict__ acts0,
                 const float4* __restrict__ chunk_t, const float4* __restrict__ bias_t,
                 const float* __restrict__ Wo,
                 float* __restrict__ out, unsigned int* __restrict__ nopen_g)
{
    __shared__ float4 stg[3][32][64];          // 98304 B
    __shared__ float  xb[2*4*NSW*5*64];        // 40960 B

    const int tid  = threadIdx.x;
    const int lane = tid & 63;
    const int w    = tid >> 6;
    const int g    = w & 3;
    const int b0   = blockIdx.x * NSB_V8 + g * NSW;

    if (w < 4) rn8_path<0>(acts0, chunk_t, bias_t, Wo, out, nopen_g,
                           &stg[0][0][0], xb, lane, w, g, b0);
    else       rn8_path<1>(acts0, chunk_t, bias_t, Wo, out, nopen_g,
                           &stg[0][0][0], xb, lane, w, g, b0);
}

// ---------------- Fallback kernel (no-workspace path): v5-style LDS staging ----------------
__global__ __launch_bounds__(256, 2)
void routenet_v5f(const float* __restrict__ acts0,
                  const float* __restrict__ x, const float* __restrict__ Wi,
                  const float* __restrict__ bi,
                  const float* __restrict__ Wg, const float* __restrict__ bg,
                  const float* __restrict__ Wd, const float* __restrict__ Wo,
                  float* __restrict__ out, unsigned int* __restrict__ nopen_g)
{
    __shared__ float4 wdstage[2][28][64];
    __shared__ float4 biasbuf[2][2][64];
    __shared__ float  exch[2][NSW][5][64];

    const int tid  = threadIdx.x;
    const int lane = tid & 63;
    const int w    = tid >> 6;
    const int g    = w & 1;
    const int h    = w >> 1;
    const int b0   = blockIdx.x * NSB_V5 + g * NSW;

    float a[NSW][DD];

    if (acts0) {
#pragma unroll
        for (int s = 0; s < NSW; ++s) {
            const float2* p = (const float2*)(acts0 + (size_t)(b0 + s) * NBF + lane * DD);
#pragma unroll
            for (int d2 = 0; d2 < 5; ++d2) {
                float2 v = p[d2];
                a[s][d2*2]   = v.x;
                a[s][d2*2+1] = v.y;
            }
        }
    } else {
        for (int s = 0; s < NSW; ++s) {
            const float* xb2 = x + (size_t)(b0 + s) * NIN;
            for (int d = 0; d < DD; ++d) {
                int n = lane * DD + d;
                const float* wr = Wi + (size_t)n * NIN;
                float z = bi[n];
                for (int i = 0; i < NIN; ++i) z = fmaf(xb2[i], wr[i], z);
                a[s][d] = fmaxf(z, 0.f);
            }
        }
    }

    float gsum[NSW];
#pragma unroll
    for (int s = 0; s < NSW; ++s) gsum[s] = 0.f;
    unsigned int nop = 0;

    auto stage_chunk = [&](int l, int k, int pdst) {
        const float* wd_base = Wd + (size_t)l * (BANKS*FAN*DD*DD)
                                  + (size_t)lane * (FAN*DD*DD) + k * (DD*DD);
        const float* wg_base = Wg + (size_t)l * (BANKS*FAN*DD)
                                  + lane * (FAN*DD) + ((10*k) >> 2) * 4;
#pragma unroll
        for (int j = 0; j < 7; ++j) {
            int r = w + 4 * j;
            if (r < 25) gll16(wd_base + r * 4, &wdstage[pdst][r][0]);
            else        gll16(wg_base + (r - 25) * 4, &wdstage[pdst][r][0]);
        }
    };
    auto stage_bias = [&](int l) {
        int q = w & 1;
        gll16(bg + (size_t)l * (BANKS*FAN) + lane * FAN + q * 4,
              &biasbuf[l & 1][q][0]);
    };

    stage_chunk(0, 0, 0);
    stage_bias(0);
    asm volatile("s_waitcnt vmcnt(0)" ::: "memory");
    asm volatile("s_barrier" ::: "memory");

    for (int l = 0; l < NLAYER; ++l) {
        const int lp = l & 1;
        float acc[NSW][5];
#pragma unroll
        for (int s = 0; s < NSW; ++s)
#pragma unroll
            for (int el = 0; el < 5; ++el) acc[s][el] = 0.f;

        auto chunk_body = [&](auto Hc, int k, int p) {
            constexpr int H = Hc.value;
            float4 wgq[3];
#pragma unroll
            for (int q = 0; q < 3; ++q) wgq[q] = wdstage[p][25 + q][lane];
            const float bias = f4c_rt(biasbuf[lp][(k >> 2) & 1][lane], k & 3);
            float wgv[DD];
            if ((k & 1) == 0) {
#pragma unroll
                for (int d = 0; d < DD; ++d) wgv[d] = f4c_rt(wgq[d >> 2], d & 3);
            } else {
#pragma unroll
                for (int d = 0; d < DD; ++d) wgv[d] = f4c_rt(wgq[(d+2) >> 2], (d+2) & 3);
            }

            float gz[NSW];
#pragma unroll
            for (int s = 0; s < NSW; ++s) {
                float z = bias;
#pragma unroll
                for (int d = 0; d < DD; ++d) z = fmaf(a[s][d], wgv[d], z);
                float gate = fminf(fmaxf(z, 0.f), 1.f);
                if (H == 0) { gsum[s] += gate; nop += (z > 0.f) ? 1u : 0u; }
                gz[s] = gate;
            }

            float4 wv[13];
#pragma unroll
            for (int i = 0; i < 13; ++i) wv[i] = wdstage[p][12*H + i][lane];

            const int src = (lane - k) & 63;
#pragma unroll
            for (int el = 0; el < 5; ++el) {
#pragma unroll
                for (int s = 0; s < NSW; ++s) {
                    float dot = 0.f;
#pragma unroll
                    for (int d = 0; d < DD; ++d) {
                        const int idx = (5*H + el) * 10 + d - 48*H;
                        dot = fmaf(a[s][d], f4c_rt(wv[idx >> 2], idx & 3), dot);
                    }
                    acc[s][el] += __shfl(gz[s] * dot, src, 64);
                }
            }
        };

#pragma unroll
        for (int c = 0; c < 8; ++c) {
            const int p = c & 1;
            if (c < 7) {
                stage_chunk(l, c + 1, p ^ 1);
                asm volatile("s_waitcnt vmcnt(7)" ::: "memory");
            } else if (l + 1 < NLAYER) {
                stage_chunk(l + 1, 0, p ^ 1);
                stage_bias(l + 1);
                asm volatile("s_waitcnt vmcnt(8)" ::: "memory");
            } else {
                asm volatile("s_waitcnt vmcnt(0)" ::: "memory");
            }
            asm volatile("s_barrier" ::: "memory");

            if (h == 0) chunk_body(std::integral_constant<int,0>{}, c, p);
            else        chunk_body(std::integral_constant<int,1>{}, c, p);

            if (c < 7) {
                asm volatile("s_waitcnt lgkmcnt(0)" ::: "memory");
                asm volatile("s_barrier" ::: "memory");
            }
        }

        if (h == 0) {
#pragma unroll
            for (int s = 0; s < NSW; ++s)
#pragma unroll
                for (int el = 0; el < 5; ++el)
                    a[s][el] = fmaxf(acc[s][el], 0.f);
        } else {
#pragma unroll
            for (int s = 0; s < NSW; ++s)
#pragma unroll
                for (int el = 0; el < 5; ++el) {
                    a[s][5 + el] = fmaxf(acc[s][el], 0.f);
                    exch[g][s][el][lane] = a[s][5 + el];
                }
        }
        asm volatile("s_waitcnt lgkmcnt(0)" ::: "memory");
        asm volatile("s_barrier" ::: "memory");

        if (h == 0) {
#pragma unroll
            for (int s = 0; s < NSW; ++s)
#pragma unroll
                for (int el = 0; el < 5; ++el)
                    a[s][5 + el] = exch[g][s][el][lane];
            if (l + 1 < NLAYER) {
#pragma unroll
                for (int s = 0; s < NSW; ++s)
#pragma unroll
                    for (int el = 0; el < 5; ++el)
                        exch[g][s][el][lane] = a[s][el];
            }
        }
        if (l + 1 < NLAYER) {
            asm volatile("s_waitcnt lgkmcnt(0)" ::: "memory");
            asm volatile("s_barrier" ::: "memory");
            if (h == 1) {
#pragma unroll
                for (int s = 0; s < NSW; ++s)
#pragma unroll
                    for (int el = 0; el < 5; ++el)
                        a[s][el] = exch[g][s][el][lane];
            }
        }
    }

    if (h == 0) {
        float wo[DD];
        const float2* p = (const float2*)(Wo + lane * DD);
#pragma unroll
        for (int d2 = 0; d2 < 5; ++d2) {
            float2 v = p[d2];
            wo[d2*2] = v.x; wo[d2*2+1] = v.y;
        }
#pragma unroll
        for (int s = 0; s < NSW; ++s) {
            float v = 0.f;
#pragma unroll
            for (int d = 0; d < DD; ++d) v = fmaf(a[s][d], wo[d], v);
            out[(size_t)(b0 + s) * BANKS + lane] = fmaxf(v, 0.f);
        }

#pragma unroll
        for (int s = 0; s < NSW; ++s) {
            float v = gsum[s];
#pragma unroll
            for (int off = 32; off; off >>= 1) v += __shfl_xor(v, off, 64);
            if (lane == 0)
                out[(size_t)4096 * BANKS + b0 + s] = v * (1.0f / 7680.0f);
        }
        {
            unsigned int v = nop;
#pragma unroll
            for (int off = 32; off; off >>= 1) v += __shfl_xor(v, off, 64);
            if (lane == 0) atomicAdd(nopen_g, v);
        }
    }
}

// ---------------- Kernel C: finalize scalar ----------------
__global__ void finalize_prob(const unsigned int* __restrict__ nopen,
                              float* __restrict__ out)
{
    out[4096*64 + 4096] = (float)(*nopen) / 31457280.0f;  // /(7680*4096)
}

extern "C" void kernel_launch(void* const* d_in, const int* in_sizes, int n_in,
                              void* d_out, int out_size, void* d_ws, size_t ws_size,
                              hipStream_t stream)
{
    const float* x  = (const float*)d_in[0];
    const float* Wi = (const float*)d_in[1];
    const float* bi = (const float*)d_in[2];
    const float* Wg = (const float*)d_in[3];
    const float* bg = (const float*)d_in[4];
    const float* Wd = (const float*)d_in[5];
    const float* Wo = (const float*)d_in[6];
    float* out = (float*)d_out;

    const size_t ACTS_BYTES  = (size_t)4096 * NBF * 4;          // 10485760
    const size_t CHUNK_BYTES = (size_t)NCH * 16;                //  3440640
    const size_t BIAS_BYTES  = (size_t)NBI * 16;                //    30720
    const size_t FULL_BYTES  = ACTS_BYTES + CHUNK_BYTES + BIAS_BYTES + 64;

    bool full    = ws_size >= FULL_BYTES;
    bool actonly = !full && ws_size >= ACTS_BYTES + 64;

    float* acts0 = (full || actonly) ? (float*)d_ws : nullptr;
    float4* chunk_t = full ? (float4*)((char*)d_ws + ACTS_BYTES) : nullptr;
    float4* bias_t  = full ? (float4*)((char*)d_ws + ACTS_BYTES + CHUNK_BYTES) : nullptr;
    unsigned int* nopen = full
        ? (unsigned int*)((char*)d_ws + ACTS_BYTES + CHUNK_BYTES + BIAS_BYTES)
        : (actonly ? (unsigned int*)((char*)d_ws + ACTS_BYTES)
                   : (unsigned int*)d_ws);

    hipMemsetAsync(nopen, 0, 4, stream);

    if (acts0) {
        dim3 grid(4096 / BM, NBF / BN);
        input_gemm<<<grid, 256, 0, stream>>>(x, Wi, bi, acts0);
    }
    if (full) {
        transpose_weights<<<(NCH + NBI + 255) / 256, 256, 0, stream>>>(
            Wg, bg, Wd, chunk_t, bias_t);
        routenet_v8<<<4096 / NSB_V8, 512, 0, stream>>>(
            acts0, chunk_t, bias_t, Wo, out, nopen);
    } else {
        routenet_v5f<<<4096 / NSB_V5, 256, 0, stream>>>(
            acts0, x, Wi, bi, Wg, bg, Wd, Wo, out, nopen);
    }
    finalize_prob<<<1, 1, 0, stream>>>(nopen, out);
}

// Round 9
// 298.112 us; speedup vs baseline: 1.5302x; 1.5302x over previous
//
#include <hip/hip_runtime.h>
#include <type_traits>

#define NIN 784
#define BANKS 64
#define NLAYER 15
#define FAN 8
#define DD 10
#define NBF 640             // features per sample per layer
#define NSW 4               // samples per sample-group (per wave)
#define NSB 8               // samples per block (2 groups x 4)

typedef float f32x2 __attribute__((ext_vector_type(2)));

// ---------------- Kernel A: input GEMM (pk-packed) ----------------
#define BM 128
#define BN 64
#define BK 16

__global__ __launch_bounds__(256)
void input_gemm(const float* __restrict__ x, const float* __restrict__ Wi,
                const float* __restrict__ bi, float* __restrict__ acts)
{
    __shared__ float As[BK][BM + 4];
    __shared__ float Bs[BK][BN + 4];
    const int tid = threadIdx.x;
    const int tx = tid & 15, ty = tid >> 4;
    const int m0 = blockIdx.x * BM;
    const int n0 = blockIdx.y * BN;

    f32x2 acc2[8][2];
#pragma unroll
    for (int i = 0; i < 8; ++i)
#pragma unroll
        for (int j = 0; j < 2; ++j) acc2[i][j] = f32x2{0.f, 0.f};

    for (int kb = 0; kb < NIN / BK; ++kb) {
#pragma unroll
        for (int i = 0; i < 2; ++i) {
            int flat = tid + 256 * i;
            int m = flat >> 2, kq = flat & 3;
            float4 v = *(const float4*)(x + (m0 + m) * NIN + kb * BK + kq * 4);
            As[kq*4+0][m] = v.x; As[kq*4+1][m] = v.y;
            As[kq*4+2][m] = v.z; As[kq*4+3][m] = v.w;
        }
        {
            int n = tid >> 2, kq = tid & 3;
            float4 v = *(const float4*)(Wi + (n0 + n) * NIN + kb * BK + kq * 4);
            Bs[kq*4+0][n] = v.x; Bs[kq*4+1][n] = v.y;
            Bs[kq*4+2][n] = v.z; Bs[kq*4+3][n] = v.w;
        }
        __syncthreads();
#pragma unroll
        for (int k = 0; k < BK; ++k) {
            float4 a0 = *(const float4*)(&As[k][ty*8]);
            float4 a1 = *(const float4*)(&As[k][ty*8+4]);
            float4 bb = *(const float4*)(&Bs[k][tx*4]);
            float av[8] = {a0.x,a0.y,a0.z,a0.w,a1.x,a1.y,a1.z,a1.w};
            f32x2 bv2[2] = { f32x2{bb.x, bb.y}, f32x2{bb.z, bb.w} };
#pragma unroll
            for (int i = 0; i < 8; ++i) {
                f32x2 ai = f32x2{av[i], av[i]};
#pragma unroll
                for (int j = 0; j < 2; ++j)
                    acc2[i][j] = __builtin_elementwise_fma(ai, bv2[j], acc2[i][j]);
            }
        }
        __syncthreads();
    }
    float4 bv = *(const float4*)(bi + n0 + tx*4);
#pragma unroll
    for (int i = 0; i < 8; ++i) {
        int row = m0 + ty*8 + i;
        float4 o;
        o.x = fmaxf(acc2[i][0][0] + bv.x, 0.f);
        o.y = fmaxf(acc2[i][0][1] + bv.y, 0.f);
        o.z = fmaxf(acc2[i][1][0] + bv.z, 0.f);
        o.w = fmaxf(acc2[i][1][1] + bv.w, 0.f);
        *(float4*)(acts + row * NBF + n0 + tx*4) = o;
    }
}

__device__ __forceinline__ float f4c_rt(const float4& v, int c) {
    return c == 0 ? v.x : (c == 1 ? v.y : (c == 2 ? v.z : v.w));
}

typedef const __attribute__((address_space(1))) void gas_void;
typedef __attribute__((address_space(3))) void las_void;

__device__ __forceinline__ void gll16(const void* g, void* l) {
    __builtin_amdgcn_global_load_lds((gas_void*)g, (las_void*)l, 16, 0, 0);
}

// ---------------- Kernel T: weight pre-transpose ----------------
// chunk_t[l][k][r=0..27][bank] float4:
//   r<25 : Wd[l][bank][k] floats 4r..4r+3
//   r>=25: Wg[l][bank][k] floats 4(r-25)..+3 (zero-padded past 10)
// bias_t[l][q=0..1][bank] float4 = bg[l][bank][4q..4q+3]
#define NCH (NLAYER*FAN*28*64)   // 215040
#define NBI (NLAYER*2*64)        // 1920

__global__ __launch_bounds__(256)
void transpose_weights(const float* __restrict__ Wg, const float* __restrict__ bg,
                       const float* __restrict__ Wd,
                       float4* __restrict__ chunk_t, float4* __restrict__ bias_t)
{
    int tid = blockIdx.x * 256 + threadIdx.x;
    if (tid < NCH) {
        int b = tid & 63;
        int rk = tid >> 6;
        int r = rk % 28;
        int lk = rk / 28;           // l*8+k
        int k = lk & 7;
        int l = lk >> 3;
        float4 v;
        if (r < 25) {
            v = ((const float4*)Wd)[(((size_t)(l*64+b)*8 + k)*25) + r];
        } else {
            int q = r - 25;
            size_t base = ((size_t)(l*64+b)*8 + k)*10 + 4*q;
            float t[4];
#pragma unroll
            for (int c = 0; c < 4; ++c)
                t[c] = (4*q + c < 10) ? Wg[base + c] : 0.f;
            v = make_float4(t[0], t[1], t[2], t[3]);
        }
        chunk_t[tid] = v;
    } else if (tid < NCH + NBI) {
        int t2 = tid - NCH;
        int b = t2 & 63;
        int q = (t2 >> 6) & 1;
        int l = t2 >> 7;
        bias_t[t2] = ((const float4*)bg)[(size_t)(l*64+b)*2 + q];
    }
}

// ---------------- Kernel B (v9): v5 structure + pk-FMA packing ----------------
// Identical staging/barrier/vmcnt schedule to v5 (proven). Only change: the 4
// samples are packed into 2 x f32x2 so gate/data dots use v_pk_fma_f32.
// Per-sample FMA chain order unchanged -> bit-identical output.
__global__ __launch_bounds__(256, 2)
void routenet_v9(const float* __restrict__ acts0,
                 const float4* __restrict__ chunk_t, const float4* __restrict__ bias_t,
                 const float* __restrict__ Wo,
                 float* __restrict__ out, unsigned int* __restrict__ nopen_g)
{
    __shared__ float4 wdstage[2][28][64];  // 57344 B (rows 0-24 Wd, 25-27 Wg)
    __shared__ float4 biasbuf[2][2][64];   //  4096 B [layer parity][q][bank]
    __shared__ float  exch[2][NSW][5][64]; // 10240 B [g][s][el][bank]

    const int tid  = threadIdx.x;
    const int lane = tid & 63;
    const int w    = tid >> 6;
    const int g    = w & 1;
    const int h    = w >> 1;
    const int b0   = blockIdx.x * NSB + g * NSW;

    // packed activations: A2[p][d] = {a(2p)[d], a(2p+1)[d]}
    f32x2 A2[2][DD];
#pragma unroll
    for (int p = 0; p < 2; ++p) {
        const float2* q0 = (const float2*)(acts0 + (size_t)(b0 + 2*p    ) * NBF + lane * DD);
        const float2* q1 = (const float2*)(acts0 + (size_t)(b0 + 2*p + 1) * NBF + lane * DD);
#pragma unroll
        for (int d2 = 0; d2 < 5; ++d2) {
            float2 v0 = q0[d2], v1 = q1[d2];
            A2[p][2*d2  ] = f32x2{v0.x, v1.x};
            A2[p][2*d2+1] = f32x2{v0.y, v1.y};
        }
    }

    f32x2 gs2[2] = { f32x2{0.f,0.f}, f32x2{0.f,0.f} };
    unsigned int nop = 0;

    auto stage_chunk = [&](int l, int k, int pdst) {
        const float4* base = chunk_t + (size_t)(l*8 + k) * 28 * 64;
#pragma unroll
        for (int j = 0; j < 7; ++j) {
            int r = w + 4 * j;
            gll16(base + r*64 + lane, &wdstage[pdst][r][0]);
        }
    };
    auto stage_bias = [&](int l) {
        int q = w & 1;   // waves 0,2 -> q0; 1,3 -> q1 (duplicate, idempotent)
        gll16(bias_t + (size_t)(l*2 + q)*64 + lane, &biasbuf[l & 1][q][0]);
    };

    stage_chunk(0, 0, 0);
    stage_bias(0);
    asm volatile("s_waitcnt vmcnt(0)" ::: "memory");
    asm volatile("s_barrier" ::: "memory");

    for (int l = 0; l < NLAYER; ++l) {
        const int lp = l & 1;
        f32x2 acc2[2][5];
#pragma unroll
        for (int p = 0; p < 2; ++p)
#pragma unroll
            for (int el = 0; el < 5; ++el) acc2[p][el] = f32x2{0.f, 0.f};

        auto chunk_body = [&](auto Hc, int k, int p) {
            constexpr int H = Hc.value;
            float4 wgq[3];
#pragma unroll
            for (int q = 0; q < 3; ++q) wgq[q] = wdstage[p][25 + q][lane];
            const float bias = f4c_rt(biasbuf[lp][(k >> 2) & 1][lane], k & 3);
            float wgv[DD];
#pragma unroll
            for (int d = 0; d < DD; ++d) wgv[d] = f4c_rt(wgq[d >> 2], d & 3);

            f32x2 gz[2];
#pragma unroll
            for (int pp = 0; pp < 2; ++pp) {
                f32x2 z = f32x2{bias, bias};
#pragma unroll
                for (int d = 0; d < DD; ++d)
                    z = __builtin_elementwise_fma(A2[pp][d], f32x2{wgv[d], wgv[d]}, z);
                f32x2 gate = __builtin_elementwise_min(
                                 __builtin_elementwise_max(z, f32x2{0.f, 0.f}),
                                 f32x2{1.f, 1.f});
                if (H == 0) {
                    gs2[pp] += gate;
                    nop += (z[0] > 0.f) ? 1u : 0u;
                    nop += (z[1] > 0.f) ? 1u : 0u;
                }
                gz[pp] = gate;
            }

            float4 wv[13];
#pragma unroll
            for (int i = 0; i < 13; ++i) wv[i] = wdstage[p][12*H + i][lane];

            const int src = (lane - k) & 63;
#pragma unroll
            for (int el = 0; el < 5; ++el) {
#pragma unroll
                for (int pp = 0; pp < 2; ++pp) {
                    f32x2 dot = f32x2{0.f, 0.f};
#pragma unroll
                    for (int d = 0; d < DD; ++d) {
                        const int idx = (5*H + el) * 10 + d - 48*H;
                        const float wd = f4c_rt(wv[idx >> 2], idx & 3);
                        dot = __builtin_elementwise_fma(A2[pp][d], f32x2{wd, wd}, dot);
                    }
                    f32x2 cc = gz[pp] * dot;
                    f32x2 r;
                    r[0] = __shfl(cc[0], src, 64);
                    r[1] = __shfl(cc[1], src, 64);
                    acc2[pp][el] += r;
                }
            }
        };

#pragma unroll
        for (int c = 0; c < 8; ++c) {
            const int p = c & 1;
            if (c < 7) {
                stage_chunk(l, c + 1, p ^ 1);
                asm volatile("s_waitcnt vmcnt(7)" ::: "memory");
            } else if (l + 1 < NLAYER) {
                stage_chunk(l + 1, 0, p ^ 1);
                stage_bias(l + 1);
                asm volatile("s_waitcnt vmcnt(8)" ::: "memory");
            } else {
                asm volatile("s_waitcnt vmcnt(0)" ::: "memory");
            }
            asm volatile("s_barrier" ::: "memory");

            if (h == 0) chunk_body(std::integral_constant<int,0>{}, c, p);
            else        chunk_body(std::integral_constant<int,1>{}, c, p);

            if (c < 7) {
                asm volatile("s_waitcnt lgkmcnt(0)" ::: "memory");
                asm volatile("s_barrier" ::: "memory");
            }
        }

        // ReLU own half; phase A: h=1 publishes its half (d=5..9)
        if (h == 0) {
#pragma unroll
            for (int s = 0; s < NSW; ++s)
#pragma unroll
                for (int el = 0; el < 5; ++el)
                    A2[s>>1][el][s&1] = fmaxf(acc2[s>>1][el][s&1], 0.f);
        } else {
#pragma unroll
            for (int s = 0; s < NSW; ++s)
#pragma unroll
                for (int el = 0; el < 5; ++el) {
                    float v = fmaxf(acc2[s>>1][el][s&1], 0.f);
                    A2[s>>1][5 + el][s&1] = v;
                    exch[g][s][el][lane] = v;
                }
        }
        asm volatile("s_waitcnt lgkmcnt(0)" ::: "memory");
        asm volatile("s_barrier" ::: "memory");

        if (h == 0) {
#pragma unroll
            for (int s = 0; s < NSW; ++s)
#pragma unroll
                for (int el = 0; el < 5; ++el)
                    A2[s>>1][5 + el][s&1] = exch[g][s][el][lane];
            if (l + 1 < NLAYER) {   // phase B: publish d=0..4
#pragma unroll
                for (int s = 0; s < NSW; ++s)
#pragma unroll
                    for (int el = 0; el < 5; ++el)
                        exch[g][s][el][lane] = A2[s>>1][el][s&1];
            }
        }
        if (l + 1 < NLAYER) {
            asm volatile("s_waitcnt lgkmcnt(0)" ::: "memory");
            asm volatile("s_barrier" ::: "memory");
            if (h == 1) {
#pragma unroll
                for (int s = 0; s < NSW; ++s)
#pragma unroll
                    for (int el = 0; el < 5; ++el)
                        A2[s>>1][el][s&1] = exch[g][s][el][lane];
            }
        }
    }

    // epilogue (h=0 waves have full activations)
    if (h == 0) {
        float wo[DD];
        const float2* pw = (const float2*)(Wo + lane * DD);
#pragma unroll
        for (int d2 = 0; d2 < 5; ++d2) {
            float2 v = pw[d2];
            wo[2*d2] = v.x; wo[2*d2+1] = v.y;
        }
#pragma unroll
        for (int p = 0; p < 2; ++p) {
            f32x2 o = f32x2{0.f, 0.f};
#pragma unroll
            for (int d = 0; d < DD; ++d)
                o = __builtin_elementwise_fma(A2[p][d], f32x2{wo[d], wo[d]}, o);
            out[(size_t)(b0 + 2*p    ) * BANKS + lane] = fmaxf(o[0], 0.f);
            out[(size_t)(b0 + 2*p + 1) * BANKS + lane] = fmaxf(o[1], 0.f);
        }

#pragma unroll
        for (int s = 0; s < NSW; ++s) {
            float v = gs2[s>>1][s&1];
#pragma unroll
            for (int off = 32; off; off >>= 1) v += __shfl_xor(v, off, 64);
            if (lane == 0)
                out[(size_t)4096 * BANKS + b0 + s] = v * (1.0f / 7680.0f);
        }
        {
            unsigned int v = nop;
#pragma unroll
            for (int off = 32; off; off >>= 1) v += __shfl_xor(v, off, 64);
            if (lane == 0) atomicAdd(nopen_g, v);
        }
    }
}

// ---------------- Fallback kernel (no-workspace path): v5-style LDS staging ----------------
__global__ __launch_bounds__(256, 2)
void routenet_v5f(const float* __restrict__ acts0,
                  const float* __restrict__ x, const float* __restrict__ Wi,
                  const float* __restrict__ bi,
                  const float* __restrict__ Wg, const float* __restrict__ bg,
                  const float* __restrict__ Wd, const float* __restrict__ Wo,
                  float* __restrict__ out, unsigned int* __restrict__ nopen_g)
{
    __shared__ float4 wdstage[2][28][64];
    __shared__ float4 biasbuf[2][2][64];
    __shared__ float  exch[2][NSW][5][64];

    const int tid  = threadIdx.x;
    const int lane = tid & 63;
    const int w    = tid >> 6;
    const int g    = w & 1;
    const int h    = w >> 1;
    const int b0   = blockIdx.x * NSB + g * NSW;

    float a[NSW][DD];

    if (acts0) {
#pragma unroll
        for (int s = 0; s < NSW; ++s) {
            const float2* p = (const float2*)(acts0 + (size_t)(b0 + s) * NBF + lane * DD);
#pragma unroll
            for (int d2 = 0; d2 < 5; ++d2) {
                float2 v = p[d2];
                a[s][d2*2]   = v.x;
                a[s][d2*2+1] = v.y;
            }
        }
    } else {
        for (int s = 0; s < NSW; ++s) {
            const float* xb2 = x + (size_t)(b0 + s) * NIN;
            for (int d = 0; d < DD; ++d) {
                int n = lane * DD + d;
                const float* wr = Wi + (size_t)n * NIN;
                float z = bi[n];
                for (int i = 0; i < NIN; ++i) z = fmaf(xb2[i], wr[i], z);
                a[s][d] = fmaxf(z, 0.f);
            }
        }
    }

    float gsum[NSW];
#pragma unroll
    for (int s = 0; s < NSW; ++s) gsum[s] = 0.f;
    unsigned int nop = 0;

    auto stage_chunk = [&](int l, int k, int pdst) {
        const float* wd_base = Wd + (size_t)l * (BANKS*FAN*DD*DD)
                                  + (size_t)lane * (FAN*DD*DD) + k * (DD*DD);
        const float* wg_base = Wg + (size_t)l * (BANKS*FAN*DD)
                                  + lane * (FAN*DD) + ((10*k) >> 2) * 4;
#pragma unroll
        for (int j = 0; j < 7; ++j) {
            int r = w + 4 * j;
            if (r < 25) gll16(wd_base + r * 4, &wdstage[pdst][r][0]);
            else        gll16(wg_base + (r - 25) * 4, &wdstage[pdst][r][0]);
        }
    };
    auto stage_bias = [&](int l) {
        int q = w & 1;
        gll16(bg + (size_t)l * (BANKS*FAN) + lane * FAN + q * 4,
              &biasbuf[l & 1][q][0]);
    };

    stage_chunk(0, 0, 0);
    stage_bias(0);
    asm volatile("s_waitcnt vmcnt(0)" ::: "memory");
    asm volatile("s_barrier" ::: "memory");

    for (int l = 0; l < NLAYER; ++l) {
        const int lp = l & 1;
        float acc[NSW][5];
#pragma unroll
        for (int s = 0; s < NSW; ++s)
#pragma unroll
            for (int el = 0; el < 5; ++el) acc[s][el] = 0.f;

        auto chunk_body = [&](auto Hc, int k, int p) {
            constexpr int H = Hc.value;
            float4 wgq[3];
#pragma unroll
            for (int q = 0; q < 3; ++q) wgq[q] = wdstage[p][25 + q][lane];
            const float bias = f4c_rt(biasbuf[lp][(k >> 2) & 1][lane], k & 3);
            float wgv[DD];
            if ((k & 1) == 0) {
#pragma unroll
                for (int d = 0; d < DD; ++d) wgv[d] = f4c_rt(wgq[d >> 2], d & 3);
            } else {
#pragma unroll
                for (int d = 0; d < DD; ++d) wgv[d] = f4c_rt(wgq[(d+2) >> 2], (d+2) & 3);
            }

            float gz[NSW];
#pragma unroll
            for (int s = 0; s < NSW; ++s) {
                float z = bias;
#pragma unroll
                for (int d = 0; d < DD; ++d) z = fmaf(a[s][d], wgv[d], z);
                float gate = fminf(fmaxf(z, 0.f), 1.f);
                if (H == 0) { gsum[s] += gate; nop += (z > 0.f) ? 1u : 0u; }
                gz[s] = gate;
            }

            float4 wv[13];
#pragma unroll
            for (int i = 0; i < 13; ++i) wv[i] = wdstage[p][12*H + i][lane];

            const int src = (lane - k) & 63;
#pragma unroll
            for (int el = 0; el < 5; ++el) {
#pragma unroll
                for (int s = 0; s < NSW; ++s) {
                    float dot = 0.f;
#pragma unroll
                    for (int d = 0; d < DD; ++d) {
                        const int idx = (5*H + el) * 10 + d - 48*H;
                        dot = fmaf(a[s][d], f4c_rt(wv[idx >> 2], idx & 3), dot);
                    }
                    acc[s][el] += __shfl(gz[s] * dot, src, 64);
                }
            }
        };

#pragma unroll
        for (int c = 0; c < 8; ++c) {
            const int p = c & 1;
            if (c < 7) {
                stage_chunk(l, c + 1, p ^ 1);
                asm volatile("s_waitcnt vmcnt(7)" ::: "memory");
            } else if (l + 1 < NLAYER) {
                stage_chunk(l + 1, 0, p ^ 1);
                stage_bias(l + 1);
                asm volatile("s_waitcnt vmcnt(8)" ::: "memory");
            } else {
                asm volatile("s_waitcnt vmcnt(0)" ::: "memory");
            }
            asm volatile("s_barrier" ::: "memory");

            if (h == 0) chunk_body(std::integral_constant<int,0>{}, c, p);
            else        chunk_body(std::integral_constant<int,1>{}, c, p);

            if (c < 7) {
                asm volatile("s_waitcnt lgkmcnt(0)" ::: "memory");
                asm volatile("s_barrier" ::: "memory");
            }
        }

        if (h == 0) {
#pragma unroll
            for (int s = 0; s < NSW; ++s)
#pragma unroll
                for (int el = 0; el < 5; ++el)
                    a[s][el] = fmaxf(acc[s][el], 0.f);
        } else {
#pragma unroll
            for (int s = 0; s < NSW; ++s)
#pragma unroll
                for (int el = 0; el < 5; ++el) {
                    a[s][5 + el] = fmaxf(acc[s][el], 0.f);
                    exch[g][s][el][lane] = a[s][5 + el];
                }
        }
        asm volatile("s_waitcnt lgkmcnt(0)" ::: "memory");
        asm volatile("s_barrier" ::: "memory");

        if (h == 0) {
#pragma unroll
            for (int s = 0; s < NSW; ++s)
#pragma unroll
                for (int el = 0; el < 5; ++el)
                    a[s][5 + el] = exch[g][s][el][lane];
            if (l + 1 < NLAYER) {
#pragma unroll
                for (int s = 0; s < NSW; ++s)
#pragma unroll
                    for (int el = 0; el < 5; ++el)
                        exch[g][s][el][lane] = a[s][el];
            }
        }
        if (l + 1 < NLAYER) {
            asm volatile("s_waitcnt lgkmcnt(0)" ::: "memory");
            asm volatile("s_barrier" ::: "memory");
            if (h == 1) {
#pragma unroll
                for (int s = 0; s < NSW; ++s)
#pragma unroll
                    for (int el = 0; el < 5; ++el)
                        a[s][el] = exch[g][s][el][lane];
            }
        }
    }

    if (h == 0) {
        float wo[DD];
        const float2* p = (const float2*)(Wo + lane * DD);
#pragma unroll
        for (int d2 = 0; d2 < 5; ++d2) {
            float2 v = p[d2];
            wo[d2*2] = v.x; wo[d2*2+1] = v.y;
        }
#pragma unroll
        for (int s = 0; s < NSW; ++s) {
            float v = 0.f;
#pragma unroll
            for (int d = 0; d < DD; ++d) v = fmaf(a[s][d], wo[d], v);
            out[(size_t)(b0 + s) * BANKS + lane] = fmaxf(v, 0.f);
        }

#pragma unroll
        for (int s = 0; s < NSW; ++s) {
            float v = gsum[s];
#pragma unroll
            for (int off = 32; off; off >>= 1) v += __shfl_xor(v, off, 64);
            if (lane == 0)
                out[(size_t)4096 * BANKS + b0 + s] = v * (1.0f / 7680.0f);
        }
        {
            unsigned int v = nop;
#pragma unroll
            for (int off = 32; off; off >>= 1) v += __shfl_xor(v, off, 64);
            if (lane == 0) atomicAdd(nopen_g, v);
        }
    }
}

// ---------------- Kernel C: finalize scalar ----------------
__global__ void finalize_prob(const unsigned int* __restrict__ nopen,
                              float* __restrict__ out)
{
    out[4096*64 + 4096] = (float)(*nopen) / 31457280.0f;  // /(7680*4096)
}

extern "C" void kernel_launch(void* const* d_in, const int* in_sizes, int n_in,
                              void* d_out, int out_size, void* d_ws, size_t ws_size,
                              hipStream_t stream)
{
    const float* x  = (const float*)d_in[0];
    const float* Wi = (const float*)d_in[1];
    const float* bi = (const float*)d_in[2];
    const float* Wg = (const float*)d_in[3];
    const float* bg = (const float*)d_in[4];
    const float* Wd = (const float*)d_in[5];
    const float* Wo = (const float*)d_in[6];
    float* out = (float*)d_out;

    const size_t ACTS_BYTES  = (size_t)4096 * NBF * 4;          // 10485760
    const size_t CHUNK_BYTES = (size_t)NCH * 16;                //  3440640
    const size_t BIAS_BYTES  = (size_t)NBI * 16;                //    30720
    const size_t FULL_BYTES  = ACTS_BYTES + CHUNK_BYTES + BIAS_BYTES + 64;

    bool full    = ws_size >= FULL_BYTES;
    bool actonly = !full && ws_size >= ACTS_BYTES + 64;

    float* acts0 = (full || actonly) ? (float*)d_ws : nullptr;
    float4* chunk_t = full ? (float4*)((char*)d_ws + ACTS_BYTES) : nullptr;
    float4* bias_t  = full ? (float4*)((char*)d_ws + ACTS_BYTES + CHUNK_BYTES) : nullptr;
    unsigned int* nopen = full
        ? (unsigned int*)((char*)d_ws + ACTS_BYTES + CHUNK_BYTES + BIAS_BYTES)
        : (actonly ? (unsigned int*)((char*)d_ws + ACTS_BYTES)
                   : (unsigned int*)d_ws);

    hipMemsetAsync(nopen, 0, 4, stream);

    if (acts0) {
        dim3 grid(4096 / BM, NBF / BN);
        input_gemm<<<grid, 256, 0, stream>>>(x, Wi, bi, acts0);
    }
    if (full) {
        transpose_weights<<<(NCH + NBI + 255) / 256, 256, 0, stream>>>(
            Wg, bg, Wd, chunk_t, bias_t);
        routenet_v9<<<4096 / NSB, 256, 0, stream>>>(
            acts0, chunk_t, bias_t, Wo, out, nopen);
    } else {
        routenet_v5f<<<4096 / NSB, 256, 0, stream>>>(
            acts0, x, Wi, bi, Wg, bg, Wd, Wo, out, nopen);
    }
    finalize_prob<<<1, 1, 0, stream>>>(nopen, out);
}

// Round 10
// 281.217 us; speedup vs baseline: 1.6221x; 1.0601x over previous
//
#include <hip/hip_runtime.h>
#include <type_traits>

#define NIN 784
#define BANKS 64
#define NLAYER 15
#define FAN 8
#define DD 10
#define NBF 640             // features per sample per layer
#define NSW 4               // samples per sample-group (per wave)
#define NSB 8               // samples per block (2 groups x 4)

typedef float f32x2 __attribute__((ext_vector_type(2)));

__device__ __forceinline__ float f4c_rt(const float4& v, int c) {
    return c == 0 ? v.x : (c == 1 ? v.y : (c == 2 ? v.z : v.w));
}

typedef const __attribute__((address_space(1))) void gas_void;
typedef __attribute__((address_space(3))) void las_void;

__device__ __forceinline__ void gll16(const void* g, void* l) {
    __builtin_amdgcn_global_load_lds((gas_void*)g, (las_void*)l, 16, 0, 0);
}

// chunk_t[l][k][r=0..27][bank] float4 (r<25: Wd quads; 25-27: Wg zero-padded)
// bias_t[l][q][bank] float4 = bg[l][bank][4q..4q+3]
#define NCH (NLAYER*FAN*28*64)   // 215040
#define NBI (NLAYER*2*64)        // 1920
#define GEMM_BLKS 640            // 64 M-tiles x 10 N-tiles (64x64)
#define TR_BLKS   848            // ceil((NCH+NBI)/256)

// ---------------- Fused prologue: input GEMM (64x64 tiles) + weight transpose ----------------
__global__ __launch_bounds__(256)
void fused_prologue(const float* __restrict__ x, const float* __restrict__ Wi,
                    const float* __restrict__ bi,
                    const float* __restrict__ Wg, const float* __restrict__ bg,
                    const float* __restrict__ Wd,
                    float* __restrict__ acts,
                    float4* __restrict__ chunk_t, float4* __restrict__ bias_t)
{
    if (blockIdx.x >= GEMM_BLKS) {
        // ---- transpose part ----
        int tid = (blockIdx.x - GEMM_BLKS) * 256 + threadIdx.x;
        if (tid < NCH) {
            int b = tid & 63;
            int rk = tid >> 6;
            int r = rk % 28;
            int lk = rk / 28;           // l*8+k
            int k = lk & 7;
            int l = lk >> 3;
            float4 v;
            if (r < 25) {
                v = ((const float4*)Wd)[(((size_t)(l*64+b)*8 + k)*25) + r];
            } else {
                int q = r - 25;
                size_t base = ((size_t)(l*64+b)*8 + k)*10 + 4*q;
                float t[4];
#pragma unroll
                for (int c = 0; c < 4; ++c)
                    t[c] = (4*q + c < 10) ? Wg[base + c] : 0.f;
                v = make_float4(t[0], t[1], t[2], t[3]);
            }
            chunk_t[tid] = v;
        } else if (tid < NCH + NBI) {
            int t2 = tid - NCH;
            int b = t2 & 63;
            int q = (t2 >> 6) & 1;
            int l = t2 >> 7;
            bias_t[t2] = ((const float4*)bg)[(size_t)(l*64+b)*2 + q];
        }
        return;
    }

    // ---- GEMM part: 64x64 tile, 256 threads, 4x4 per thread ----
    __shared__ float As[16][68];
    __shared__ float Bs[16][68];
    const int tid = threadIdx.x;
    const int tx = tid & 15, ty = tid >> 4;
    const int m0 = (blockIdx.x & 63) * 64;
    const int n0 = (blockIdx.x >> 6) * 64;

    float acc[4][4];
#pragma unroll
    for (int i = 0; i < 4; ++i)
#pragma unroll
        for (int j = 0; j < 4; ++j) acc[i][j] = 0.f;

    for (int kb = 0; kb < NIN / 16; ++kb) {
        {
            int m = tid >> 2, kq = tid & 3;
            float4 v = *(const float4*)(x + (m0 + m) * NIN + kb * 16 + kq * 4);
            As[kq*4+0][m] = v.x; As[kq*4+1][m] = v.y;
            As[kq*4+2][m] = v.z; As[kq*4+3][m] = v.w;
            float4 u = *(const float4*)(Wi + (n0 + m) * NIN + kb * 16 + kq * 4);
            Bs[kq*4+0][m] = u.x; Bs[kq*4+1][m] = u.y;
            Bs[kq*4+2][m] = u.z; Bs[kq*4+3][m] = u.w;
        }
        __syncthreads();
#pragma unroll
        for (int k = 0; k < 16; ++k) {
            float4 a4 = *(const float4*)(&As[k][ty*4]);
            float4 b4 = *(const float4*)(&Bs[k][tx*4]);
            float av[4] = {a4.x, a4.y, a4.z, a4.w};
            float bv[4] = {b4.x, b4.y, b4.z, b4.w};
#pragma unroll
            for (int i = 0; i < 4; ++i)
#pragma unroll
                for (int j = 0; j < 4; ++j)
                    acc[i][j] = fmaf(av[i], bv[j], acc[i][j]);
        }
        __syncthreads();
    }
    float4 bv = *(const float4*)(bi + n0 + tx*4);
#pragma unroll
    for (int i = 0; i < 4; ++i) {
        int row = m0 + ty*4 + i;
        float4 o;
        o.x = fmaxf(acc[i][0] + bv.x, 0.f);
        o.y = fmaxf(acc[i][1] + bv.y, 0.f);
        o.z = fmaxf(acc[i][2] + bv.z, 0.f);
        o.w = fmaxf(acc[i][3] + bv.w, 0.f);
        *(float4*)(acts + row * NBF + n0 + tx*4) = o;
    }
}

// ---------------- Kernel B (v10): v9 + reg-bias, merged phase-B barrier, setprio ----------------
// LDS: wdstage 57344 + exH0 10240 + exH1 10240 = 77824 B -> 2 blocks/CU.
// Barriers: 8 leading + 7 trailing + 1 exchange = 16/layer. Uniform vmcnt(7).
__global__ __launch_bounds__(256, 2)
void routenet_v10(const float* __restrict__ acts0,
                  const float4* __restrict__ chunk_t, const float4* __restrict__ bias_t,
                  const float* __restrict__ Wo,
                  float* __restrict__ out, unsigned int* __restrict__ nopen_g)
{
    __shared__ float4 wdstage[2][28][64];   // 57344 B
    __shared__ float  exH1[2][NSW][5][64];  // 10240 B  h1 -> h0 (els 5-9)
    __shared__ float  exH0[2][NSW][5][64];  // 10240 B  h0 -> h1 (els 0-4)

    const int tid  = threadIdx.x;
    const int lane = tid & 63;
    const int w    = tid >> 6;
    const int g    = w & 1;
    const int h    = w >> 1;
    const int b0   = blockIdx.x * NSB + g * NSW;

    // packed activations: A2[p][d] = {a(2p)[d], a(2p+1)[d]}
    f32x2 A2[2][DD];
#pragma unroll
    for (int p = 0; p < 2; ++p) {
        const float2* q0 = (const float2*)(acts0 + (size_t)(b0 + 2*p    ) * NBF + lane * DD);
        const float2* q1 = (const float2*)(acts0 + (size_t)(b0 + 2*p + 1) * NBF + lane * DD);
#pragma unroll
        for (int d2 = 0; d2 < 5; ++d2) {
            float2 v0 = q0[d2], v1 = q1[d2];
            A2[p][2*d2  ] = f32x2{v0.x, v1.x};
            A2[p][2*d2+1] = f32x2{v0.y, v1.y};
        }
    }

    f32x2 gs2[2] = { f32x2{0.f,0.f}, f32x2{0.f,0.f} };
    unsigned int nop = 0;

    auto stage_chunk = [&](int l, int k, int pdst) {
        const float4* base = chunk_t + (size_t)(l*8 + k) * 28 * 64;
#pragma unroll
        for (int j = 0; j < 7; ++j) {
            int r = w + 4 * j;
            gll16(base + r*64 + lane, &wdstage[pdst][r][0]);
        }
    };

    stage_chunk(0, 0, 0);
    float4 bq0 = bias_t[lane];
    float4 bq1 = bias_t[64 + lane];
    asm volatile("s_waitcnt vmcnt(0)" ::: "memory");
    asm volatile("s_barrier" ::: "memory");

    for (int l = 0; l < NLAYER; ++l) {
        // prefetch next layer's bias into regs (consumed next layer; any
        // interleave with gll16 only makes vmcnt(7) over-wait -> safe)
        float4 bn0 = bq0, bn1 = bq1;
        if (l + 1 < NLAYER) {
            bn0 = bias_t[(size_t)((l+1)*2    ) * 64 + lane];
            bn1 = bias_t[(size_t)((l+1)*2 + 1) * 64 + lane];
        }

        f32x2 acc2[2][5];
#pragma unroll
        for (int p = 0; p < 2; ++p)
#pragma unroll
            for (int el = 0; el < 5; ++el) acc2[p][el] = f32x2{0.f, 0.f};

        auto chunk_body = [&](auto Hc, int k, int p) {
            constexpr int H = Hc.value;
            float4 wgq[3];
#pragma unroll
            for (int q = 0; q < 3; ++q) wgq[q] = wdstage[p][25 + q][lane];
            const float bias = f4c_rt((k & 4) ? bq1 : bq0, k & 3);
            float wgv[DD];
#pragma unroll
            for (int d = 0; d < DD; ++d) wgv[d] = f4c_rt(wgq[d >> 2], d & 3);

            f32x2 gz[2];
#pragma unroll
            for (int pp = 0; pp < 2; ++pp) {
                f32x2 z = f32x2{bias, bias};
#pragma unroll
                for (int d = 0; d < DD; ++d)
                    z = __builtin_elementwise_fma(A2[pp][d], f32x2{wgv[d], wgv[d]}, z);
                f32x2 gate = __builtin_elementwise_min(
                                 __builtin_elementwise_max(z, f32x2{0.f, 0.f}),
                                 f32x2{1.f, 1.f});
                if (H == 0) {
                    gs2[pp] += gate;
                    nop += (z[0] > 0.f) ? 1u : 0u;
                    nop += (z[1] > 0.f) ? 1u : 0u;
                }
                gz[pp] = gate;
            }

            float4 wv[13];
#pragma unroll
            for (int i = 0; i < 13; ++i) wv[i] = wdstage[p][12*H + i][lane];

            const int src = (lane - k) & 63;
#pragma unroll
            for (int el = 0; el < 5; ++el) {
#pragma unroll
                for (int pp = 0; pp < 2; ++pp) {
                    f32x2 dot = f32x2{0.f, 0.f};
#pragma unroll
                    for (int d = 0; d < DD; ++d) {
                        const int idx = (5*H + el) * 10 + d - 48*H;
                        const float wd = f4c_rt(wv[idx >> 2], idx & 3);
                        dot = __builtin_elementwise_fma(A2[pp][d], f32x2{wd, wd}, dot);
                    }
                    f32x2 cc = gz[pp] * dot;
                    f32x2 r;
                    r[0] = __shfl(cc[0], src, 64);
                    r[1] = __shfl(cc[1], src, 64);
                    acc2[pp][el] += r;
                }
            }
        };

#pragma unroll
        for (int c = 0; c < 8; ++c) {
            const int p = c & 1;
            if (c < 7) {
                stage_chunk(l, c + 1, p ^ 1);
                asm volatile("s_waitcnt vmcnt(7)" ::: "memory");
            } else if (l + 1 < NLAYER) {
                stage_chunk(l + 1, 0, p ^ 1);
                asm volatile("s_waitcnt vmcnt(7)" ::: "memory");
            } else {
                asm volatile("s_waitcnt vmcnt(0)" ::: "memory");
            }
            if (c == 0) {
                // covers h0's late exH0 writes (phase B of previous layer)
                asm volatile("s_waitcnt lgkmcnt(0)" ::: "memory");
            }
            asm volatile("s_barrier" ::: "memory");

            __builtin_amdgcn_s_setprio(1);
            if (c == 0 && l > 0 && h == 1) {
                // pull els 0-4 published by h0 after previous layer's barrier A
#pragma unroll
                for (int s = 0; s < NSW; ++s)
#pragma unroll
                    for (int el = 0; el < 5; ++el)
                        A2[s>>1][el][s&1] = exH0[g][s][el][lane];
            }
            if (h == 0) chunk_body(std::integral_constant<int,0>{}, c, p);
            else        chunk_body(std::integral_constant<int,1>{}, c, p);
            __builtin_amdgcn_s_setprio(0);

            if (c < 7) {
                asm volatile("s_waitcnt lgkmcnt(0)" ::: "memory");
                asm volatile("s_barrier" ::: "memory");
            }
        }

        // layer end: ReLU own half; h1 publishes els 5-9
        if (h == 0) {
#pragma unroll
            for (int s = 0; s < NSW; ++s)
#pragma unroll
                for (int el = 0; el < 5; ++el)
                    A2[s>>1][el][s&1] = fmaxf(acc2[s>>1][el][s&1], 0.f);
        } else {
#pragma unroll
            for (int s = 0; s < NSW; ++s)
#pragma unroll
                for (int el = 0; el < 5; ++el) {
                    float v = fmaxf(acc2[s>>1][el][s&1], 0.f);
                    A2[s>>1][5 + el][s&1] = v;
                    exH1[g][s][el][lane] = v;
                }
        }
        asm volatile("s_waitcnt lgkmcnt(0)" ::: "memory");
        asm volatile("s_barrier" ::: "memory");    // barrier A (serves as c==7 trailing)

        if (h == 0) {
#pragma unroll
            for (int s = 0; s < NSW; ++s)
#pragma unroll
                for (int el = 0; el < 5; ++el)
                    A2[s>>1][5 + el][s&1] = exH1[g][s][el][lane];
            if (l + 1 < NLAYER) {   // phase B publish: consumed after next chunk-0 barrier
#pragma unroll
                for (int s = 0; s < NSW; ++s)
#pragma unroll
                    for (int el = 0; el < 5; ++el)
                        exH0[g][s][el][lane] = A2[s>>1][el][s&1];
            }
        }
        bq0 = bn0; bq1 = bn1;
    }

    // epilogue (h=0 waves have full activations)
    if (h == 0) {
        float wo[DD];
        const float2* pw = (const float2*)(Wo + lane * DD);
#pragma unroll
        for (int d2 = 0; d2 < 5; ++d2) {
            float2 v = pw[d2];
            wo[2*d2] = v.x; wo[2*d2+1] = v.y;
        }
#pragma unroll
        for (int p = 0; p < 2; ++p) {
            f32x2 o = f32x2{0.f, 0.f};
#pragma unroll
            for (int d = 0; d < DD; ++d)
                o = __builtin_elementwise_fma(A2[p][d], f32x2{wo[d], wo[d]}, o);
            out[(size_t)(b0 + 2*p    ) * BANKS + lane] = fmaxf(o[0], 0.f);
            out[(size_t)(b0 + 2*p + 1) * BANKS + lane] = fmaxf(o[1], 0.f);
        }

#pragma unroll
        for (int s = 0; s < NSW; ++s) {
            float v = gs2[s>>1][s&1];
#pragma unroll
            for (int off = 32; off; off >>= 1) v += __shfl_xor(v, off, 64);
            if (lane == 0)
                out[(size_t)4096 * BANKS + b0 + s] = v * (1.0f / 7680.0f);
        }
        {
            unsigned int v = nop;
#pragma unroll
            for (int off = 32; off; off >>= 1) v += __shfl_xor(v, off, 64);
            if (lane == 0) atomicAdd(nopen_g, v);
        }
    }
}

// ---------------- Fallback kernel (no-workspace path): v5-style LDS staging ----------------
__global__ __launch_bounds__(256, 2)
void routenet_v5f(const float* __restrict__ acts0,
                  const float* __restrict__ x, const float* __restrict__ Wi,
                  const float* __restrict__ bi,
                  const float* __restrict__ Wg, const float* __restrict__ bg,
                  const float* __restrict__ Wd, const float* __restrict__ Wo,
                  float* __restrict__ out, unsigned int* __restrict__ nopen_g)
{
    __shared__ float4 wdstage[2][28][64];
    __shared__ float4 biasbuf[2][2][64];
    __shared__ float  exch[2][NSW][5][64];

    const int tid  = threadIdx.x;
    const int lane = tid & 63;
    const int w    = tid >> 6;
    const int g    = w & 1;
    const int h    = w >> 1;
    const int b0   = blockIdx.x * NSB + g * NSW;

    float a[NSW][DD];

    if (acts0) {
#pragma unroll
        for (int s = 0; s < NSW; ++s) {
            const float2* p = (const float2*)(acts0 + (size_t)(b0 + s) * NBF + lane * DD);
#pragma unroll
            for (int d2 = 0; d2 < 5; ++d2) {
                float2 v = p[d2];
                a[s][d2*2]   = v.x;
                a[s][d2*2+1] = v.y;
            }
        }
    } else {
        for (int s = 0; s < NSW; ++s) {
            const float* xb2 = x + (size_t)(b0 + s) * NIN;
            for (int d = 0; d < DD; ++d) {
                int n = lane * DD + d;
                const float* wr = Wi + (size_t)n * NIN;
                float z = bi[n];
                for (int i = 0; i < NIN; ++i) z = fmaf(xb2[i], wr[i], z);
                a[s][d] = fmaxf(z, 0.f);
            }
        }
    }

    float gsum[NSW];
#pragma unroll
    for (int s = 0; s < NSW; ++s) gsum[s] = 0.f;
    unsigned int nop = 0;

    auto stage_chunk = [&](int l, int k, int pdst) {
        const float* wd_base = Wd + (size_t)l * (BANKS*FAN*DD*DD)
                                  + (size_t)lane * (FAN*DD*DD) + k * (DD*DD);
        const float* wg_base = Wg + (size_t)l * (BANKS*FAN*DD)
                                  + lane * (FAN*DD) + ((10*k) >> 2) * 4;
#pragma unroll
        for (int j = 0; j < 7; ++j) {
            int r = w + 4 * j;
            if (r < 25) gll16(wd_base + r * 4, &wdstage[pdst][r][0]);
            else        gll16(wg_base + (r - 25) * 4, &wdstage[pdst][r][0]);
        }
    };
    auto stage_bias = [&](int l) {
        int q = w & 1;
        gll16(bg + (size_t)l * (BANKS*FAN) + lane * FAN + q * 4,
              &biasbuf[l & 1][q][0]);
    };

    stage_chunk(0, 0, 0);
    stage_bias(0);
    asm volatile("s_waitcnt vmcnt(0)" ::: "memory");
    asm volatile("s_barrier" ::: "memory");

    for (int l = 0; l < NLAYER; ++l) {
        const int lp = l & 1;
        float acc[NSW][5];
#pragma unroll
        for (int s = 0; s < NSW; ++s)
#pragma unroll
            for (int el = 0; el < 5; ++el) acc[s][el] = 0.f;

        auto chunk_body = [&](auto Hc, int k, int p) {
            constexpr int H = Hc.value;
            float4 wgq[3];
#pragma unroll
            for (int q = 0; q < 3; ++q) wgq[q] = wdstage[p][25 + q][lane];
            const float bias = f4c_rt(biasbuf[lp][(k >> 2) & 1][lane], k & 3);
            float wgv[DD];
            if ((k & 1) == 0) {
#pragma unroll
                for (int d = 0; d < DD; ++d) wgv[d] = f4c_rt(wgq[d >> 2], d & 3);
            } else {
#pragma unroll
                for (int d = 0; d < DD; ++d) wgv[d] = f4c_rt(wgq[(d+2) >> 2], (d+2) & 3);
            }

            float gz[NSW];
#pragma unroll
            for (int s = 0; s < NSW; ++s) {
                float z = bias;
#pragma unroll
                for (int d = 0; d < DD; ++d) z = fmaf(a[s][d], wgv[d], z);
                float gate = fminf(fmaxf(z, 0.f), 1.f);
                if (H == 0) { gsum[s] += gate; nop += (z > 0.f) ? 1u : 0u; }
                gz[s] = gate;
            }

            float4 wv[13];
#pragma unroll
            for (int i = 0; i < 13; ++i) wv[i] = wdstage[p][12*H + i][lane];

            const int src = (lane - k) & 63;
#pragma unroll
            for (int el = 0; el < 5; ++el) {
#pragma unroll
                for (int s = 0; s < NSW; ++s) {
                    float dot = 0.f;
#pragma unroll
                    for (int d = 0; d < DD; ++d) {
                        const int idx = (5*H + el) * 10 + d - 48*H;
                        dot = fmaf(a[s][d], f4c_rt(wv[idx >> 2], idx & 3), dot);
                    }
                    acc[s][el] += __shfl(gz[s] * dot, src, 64);
                }
            }
        };

#pragma unroll
        for (int c = 0; c < 8; ++c) {
            const int p = c & 1;
            if (c < 7) {
                stage_chunk(l, c + 1, p ^ 1);
                asm volatile("s_waitcnt vmcnt(7)" ::: "memory");
            } else if (l + 1 < NLAYER) {
                stage_chunk(l + 1, 0, p ^ 1);
                stage_bias(l + 1);
                asm volatile("s_waitcnt vmcnt(8)" ::: "memory");
            } else {
                asm volatile("s_waitcnt vmcnt(0)" ::: "memory");
            }
            asm volatile("s_barrier" ::: "memory");

            if (h == 0) chunk_body(std::integral_constant<int,0>{}, c, p);
            else        chunk_body(std::integral_constant<int,1>{}, c, p);

            if (c < 7) {
                asm volatile("s_waitcnt lgkmcnt(0)" ::: "memory");
                asm volatile("s_barrier" ::: "memory");
            }
        }

        if (h == 0) {
#pragma unroll
            for (int s = 0; s < NSW; ++s)
#pragma unroll
                for (int el = 0; el < 5; ++el)
                    a[s][el] = fmaxf(acc[s][el], 0.f);
        } else {
#pragma unroll
            for (int s = 0; s < NSW; ++s)
#pragma unroll
                for (int el = 0; el < 5; ++el) {
                    a[s][5 + el] = fmaxf(acc[s][el], 0.f);
                    exch[g][s][el][lane] = a[s][5 + el];
                }
        }
        asm volatile("s_waitcnt lgkmcnt(0)" ::: "memory");
        asm volatile("s_barrier" ::: "memory");

        if (h == 0) {
#pragma unroll
            for (int s = 0; s < NSW; ++s)
#pragma unroll
                for (int el = 0; el < 5; ++el)
                    a[s][5 + el] = exch[g][s][el][lane];
            if (l + 1 < NLAYER) {
#pragma unroll
                for (int s = 0; s < NSW; ++s)
#pragma unroll
                    for (int el = 0; el < 5; ++el)
                        exch[g][s][el][lane] = a[s][el];
            }
        }
        if (l + 1 < NLAYER) {
            asm volatile("s_waitcnt lgkmcnt(0)" ::: "memory");
            asm volatile("s_barrier" ::: "memory");
            if (h == 1) {
#pragma unroll
                for (int s = 0; s < NSW; ++s)
#pragma unroll
                    for (int el = 0; el < 5; ++el)
                        a[s][el] = exch[g][s][el][lane];
            }
        }
    }

    if (h == 0) {
        float wo[DD];
        const float2* p = (const float2*)(Wo + lane * DD);
#pragma unroll
        for (int d2 = 0; d2 < 5; ++d2) {
            float2 v = p[d2];
            wo[d2*2] = v.x; wo[d2*2+1] = v.y;
        }
#pragma unroll
        for (int s = 0; s < NSW; ++s) {
            float v = 0.f;
#pragma unroll
            for (int d = 0; d < DD; ++d) v = fmaf(a[s][d], wo[d], v);
            out[(size_t)(b0 + s) * BANKS + lane] = fmaxf(v, 0.f);
        }

#pragma unroll
        for (int s = 0; s < NSW; ++s) {
            float v = gsum[s];
#pragma unroll
            for (int off = 32; off; off >>= 1) v += __shfl_xor(v, off, 64);
            if (lane == 0)
                out[(size_t)4096 * BANKS + b0 + s] = v * (1.0f / 7680.0f);
        }
        {
            unsigned int v = nop;
#pragma unroll
            for (int off = 32; off; off >>= 1) v += __shfl_xor(v, off, 64);
            if (lane == 0) atomicAdd(nopen_g, v);
        }
    }
}

// ---------------- Kernel C: finalize scalar ----------------
__global__ void finalize_prob(const unsigned int* __restrict__ nopen,
                              float* __restrict__ out)
{
    out[4096*64 + 4096] = (float)(*nopen) / 31457280.0f;  // /(7680*4096)
}

extern "C" void kernel_launch(void* const* d_in, const int* in_sizes, int n_in,
                              void* d_out, int out_size, void* d_ws, size_t ws_size,
                              hipStream_t stream)
{
    const float* x  = (const float*)d_in[0];
    const float* Wi = (const float*)d_in[1];
    const float* bi = (const float*)d_in[2];
    const float* Wg = (const float*)d_in[3];
    const float* bg = (const float*)d_in[4];
    const float* Wd = (const float*)d_in[5];
    const float* Wo = (const float*)d_in[6];
    float* out = (float*)d_out;

    const size_t ACTS_BYTES  = (size_t)4096 * NBF * 4;          // 10485760
    const size_t CHUNK_BYTES = (size_t)NCH * 16;                //  3440640
    const size_t BIAS_BYTES  = (size_t)NBI * 16;                //    30720
    const size_t FULL_BYTES  = ACTS_BYTES + CHUNK_BYTES + BIAS_BYTES + 64;

    bool full    = ws_size >= FULL_BYTES;
    bool actonly = !full && ws_size >= ACTS_BYTES + 64;

    float* acts0 = (full || actonly) ? (float*)d_ws : nullptr;
    float4* chunk_t = full ? (float4*)((char*)d_ws + ACTS_BYTES) : nullptr;
    float4* bias_t  = full ? (float4*)((char*)d_ws + ACTS_BYTES + CHUNK_BYTES) : nullptr;
    unsigned int* nopen = full
        ? (unsigned int*)((char*)d_ws + ACTS_BYTES + CHUNK_BYTES + BIAS_BYTES)
        : (actonly ? (unsigned int*)((char*)d_ws + ACTS_BYTES)
                   : (unsigned int*)d_ws);

    hipMemsetAsync(nopen, 0, 4, stream);

    if (full) {
        fused_prologue<<<GEMM_BLKS + TR_BLKS, 256, 0, stream>>>(
            x, Wi, bi, Wg, bg, Wd, acts0, chunk_t, bias_t);
        routenet_v10<<<4096 / NSB, 256, 0, stream>>>(
            acts0, chunk_t, bias_t, Wo, out, nopen);
    } else {
        if (acts0) {
            // acts-only workspace: reuse fused kernel's GEMM half via a
            // dummy-transpose-free launch is not possible; fall back to
            // in-kernel input layer when no acts buffer, else compute acts
            // with the fused kernel writing only the GEMM part.
            fused_prologue<<<GEMM_BLKS, 256, 0, stream>>>(
                x, Wi, bi, Wg, bg, Wd, acts0, nullptr, nullptr);
        }
        routenet_v5f<<<4096 / NSB, 256, 0, stream>>>(
            acts0, x, Wi, bi, Wg, bg, Wd, Wo, out, nopen);
    }
    finalize_prob<<<1, 1, 0, stream>>>(nopen, out);
}